// Round 3
// baseline (762.934 us; speedup 1.0000x reference)
//
#include <hip/hip_runtime.h>
#include <hip/hip_bf16.h>

#define HDIM 128
#define NSTAGE 7
#define CHUNK_LOG 13
#define CHUNK (1 << CHUNK_LOG)

typedef __bf16 bf16x8 __attribute__((ext_vector_type(8)));
typedef __bf16 bf16x2 __attribute__((ext_vector_type(2)));
typedef float floatx16 __attribute__((ext_vector_type(16)));
typedef float floatx4 __attribute__((ext_vector_type(4)));
typedef int intx4 __attribute__((ext_vector_type(4)));

__device__ __forceinline__ float silu_f(float x) {
    return x * __builtin_amdgcn_rcpf(1.0f + __expf(-x));
}

__device__ __forceinline__ int pack2(float a, float b) {
    bf16x2 h;
    h[0] = (__bf16)a;
    h[1] = (__bf16)b;
    return __builtin_bit_cast(int, h);
}

__device__ __forceinline__ bf16x8 frag_from(int w0, int w1, int w2, int w3) {
    intx4 v; v[0] = w0; v[1] = w1; v[2] = w2; v[3] = w3;
    return __builtin_bit_cast(bf16x8, v);
}

// Weights -> bf16, stage order W1[0],W2[0],W1[1],W2[1],W1[2],W2[2],Wlin.
// XOR swizzle on 16B chunks: [m][k] -> m*128 + ((k>>3)^(m&7))*8 + (k&7).
__global__ void convert_weights(const float* __restrict__ W1,
                                const float* __restrict__ W2,
                                const float* __restrict__ Wlin,
                                __bf16* __restrict__ dst) {
    int idx = blockIdx.x * blockDim.x + threadIdx.x;
    if (idx >= NSTAGE * HDIM * HDIM) return;
    int s    = idx >> 14;
    int rem  = idx & 16383;
    int mrow = rem >> 7;
    int k    = rem & 127;
    const float* src;
    if (s == 6) src = Wlin;
    else {
        int l = s >> 1;
        src = ((s & 1) ? W2 : W1) + l * HDIM * HDIM;
    }
    float v = src[mrow * HDIM + k];
    int dsti = (s << 14) + (mrow << 7) + ((((k >> 3) ^ (mrow & 7)) << 3) | (k & 7));
    dst[dsti] = (__bf16)v;
}

// ---- atomic-free counting sort of edges by target node ----
__global__ __launch_bounds__(1024) void hist_rank_kernel(
    const int* __restrict__ tgt,
    unsigned short* __restrict__ rank,
    int* __restrict__ hb,
    int E, int N)
{
    __shared__ int lh[10240];   // N = 10000 for this problem
    for (int i = threadIdx.x; i < N; i += 1024) lh[i] = 0;
    __syncthreads();
    int ebase = blockIdx.x << CHUNK_LOG;
    int eend  = min(ebase + CHUNK, E);
    for (int e = ebase + (int)threadIdx.x; e < eend; e += 1024) {
        int node = tgt[e];
        int r = atomicAdd(&lh[node], 1);   // LDS atomic — fast
        rank[e] = (unsigned short)r;       // coalesced
    }
    __syncthreads();
    int* row = hb + (size_t)blockIdx.x * N;
    for (int i = threadIdx.x; i < N; i += 1024) row[i] = lh[i];  // coalesced
}

__global__ void colsum_kernel(const int* __restrict__ hb, int* __restrict__ tot,
                              int nblk, int N) {
    int n = blockIdx.x * blockDim.x + threadIdx.x;
    if (n >= N) return;
    int s = 0;
    for (int b = 0; b < nblk; ++b) s += hb[(size_t)b * N + n];
    tot[n] = s;
}

__global__ __launch_bounds__(1024) void scan_kernel(const int* __restrict__ hist,
                                                    int* __restrict__ cursor, int N) {
    __shared__ int part[1024];
    int t = threadIdx.x;
    int per = (N + 1023) >> 10;
    int lo = t * per, hi = min(lo + per, N);
    int s = 0;
    for (int i = lo; i < hi; ++i) s += hist[i];
    part[t] = s;
    __syncthreads();
    for (int d = 1; d < 1024; d <<= 1) {
        int v = (t >= d) ? part[t - d] : 0;
        __syncthreads();
        part[t] += v;
        __syncthreads();
    }
    int off = (t == 0) ? 0 : part[t - 1];
    for (int i = lo; i < hi; ++i) { cursor[i] = off; off += hist[i]; }
}

__global__ void offsets_kernel(int* __restrict__ hb, const int* __restrict__ base,
                               int nblk, int N) {
    int n = blockIdx.x * blockDim.x + threadIdx.x;
    if (n >= N) return;
    int run = base[n];
    for (int b = 0; b < nblk; ++b) {
        size_t idx = (size_t)b * N + n;
        int c = hb[idx];
        hb[idx] = run;
        run += c;
    }
}

__global__ void emit_perm_kernel(const int* __restrict__ tgt,
                                 const unsigned short* __restrict__ rank,
                                 const int* __restrict__ hb,
                                 int* __restrict__ perm, int* __restrict__ snode,
                                 int E, int N) {
    int e = blockIdx.x * blockDim.x + threadIdx.x;
    if (e >= E) return;
    int node = tgt[e];
    int b = e >> CHUNK_LOG;
    int pos = hb[(size_t)b * N + node] + (int)rank[e];
    perm[pos] = e;
    snode[pos] = node;
}

// One wave owns 32 sorted-order edges end-to-end; residual X in fp32 regs.
// Matmuls transposed: D[feat][edge] via mfma_f32_32x32x16_bf16.
// C/D: edge=lane&31, feat=mb*32+(reg&3)+8*(reg>>2)+4*(lane>>5).
//
// Activations live ENTIRELY IN REGISTERS. B-fragment for k-group ks needs
// feats f = ks*16 + half*8 + j of the lane's own edge (l31). In acc-speak
// those are quad q(half)=(ks&1)*2+half: elems j0..3 held by the half=0 lane
// (h'=0) and j4..7 by the half=1 lane (h'=1). The cross-half exchange is
// done with __shfl_xor(.,32) (ds_bpermute — unambiguous semantics) plus
// cndmask selects:
//   A0/A1 = own packs of quad qa, B0/B1 = quad qb
//   N = the pack the PARTNER needs = half ? A : B ; S = shfl_xor(N, 32)
//   word0 = half ? S0 : A0   word1 = half ? S1 : A1    (h'=0 source)
//   word2 = half ? B0 : S0   word3 = half ? B1 : S1    (h'=1 source)
// Bias is folded into the MFMA C-init. No act LDS => no act bank conflicts,
// and smem shrinks to 36864 B (wlds 32K + 2-pass epilogue buffer overlay)
// => 3 blocks/CU instead of 2.
__global__ __launch_bounds__(256, 3) void fused_mlp_scatter(
    const float* __restrict__ m,
    const int* __restrict__ perm,
    const int* __restrict__ snode,
    const __bf16* __restrict__ wmats,
    const float* __restrict__ b1,
    const float* __restrict__ b2,
    const float* __restrict__ blin,
    float* __restrict__ out,
    int E, int ntiles)
{
    __shared__ __align__(16) char smem[36864];
    __bf16* wlds = (__bf16*)smem;                  // 32 KB (stages)
    float*  ybuf = (float*)smem;                   // 4*32*72 f32 (epilogue overlay)

    const int tid  = threadIdx.x;
    const int w    = tid >> 6;
    const int lane = tid & 63;
    const int l31  = lane & 31;
    const int half = lane >> 5;

    const int tile    = blockIdx.x * 4 + w;
    const bool activeW = (tile < ntiles);
    const int pos = tile * 32 + l31;
    const bool evalid = activeW && (pos < E);

    int eidx = 0, mynode = 0;
    if (evalid) { eidx = perm[pos]; mynode = snode[pos]; }

    floatx4 X[4][4];
    floatx16 acc[4];
    bf16x8 wpre[8];
    int bw[8][4];   // B-fragments for current stage, fully static-indexed

    #define BUILD_BW(KS, VA0,VA1,VA2,VA3, VB0,VB1,VB2,VB3) do {              \
        int A0_ = pack2((VA0), (VA1)); int A1_ = pack2((VA2), (VA3));        \
        int B0_ = pack2((VB0), (VB1)); int B1_ = pack2((VB2), (VB3));        \
        int N0_ = half ? A0_ : B0_;  int N1_ = half ? A1_ : B1_;             \
        int S0_ = __shfl_xor(N0_, 32, 64);                                   \
        int S1_ = __shfl_xor(N1_, 32, 64);                                   \
        bw[KS][0] = half ? S0_ : A0_;  bw[KS][1] = half ? S1_ : A1_;         \
        bw[KS][2] = half ? B0_ : S0_;  bw[KS][3] = half ? B1_ : S1_;         \
    } while (0)

    // prefetch stage-0 W tile into registers (all 256 threads)
    #pragma unroll
    for (int i = 0; i < 8; ++i)
        wpre[i] = *(const bf16x8*)(wmats + i * 2048 + tid * 8);

    if (activeW) {
        const float* mrow = m + (size_t)eidx * HDIM;
        #pragma unroll
        for (int mb = 0; mb < 4; ++mb)
            #pragma unroll
            for (int q = 0; q < 4; ++q) {
                int f0 = mb * 32 + q * 8 + half * 4;
                X[mb][q] = *(const floatx4*)(mrow + f0);
            }
        // initial activations: silu(X) -> in-register B-fragments
        #pragma unroll
        for (int ks = 0; ks < 8; ++ks) {
            int mb = ks >> 1, qa = (ks & 1) * 2, qb = qa + 1;
            BUILD_BW(ks,
                silu_f(X[mb][qa][0]), silu_f(X[mb][qa][1]),
                silu_f(X[mb][qa][2]), silu_f(X[mb][qa][3]),
                silu_f(X[mb][qb][0]), silu_f(X[mb][qb][1]),
                silu_f(X[mb][qb][2]), silu_f(X[mb][qb][3]));
        }
    }

    #pragma unroll
    for (int s = 0; s < NSTAGE; ++s) {
        __syncthreads();   // all waves done reading wlds from previous stage
        #pragma unroll
        for (int i = 0; i < 8; ++i)
            *(bf16x8*)(&wlds[i * 2048 + tid * 8]) = wpre[i];
        __syncthreads();
        // issue next stage's W loads now; vmcnt drains during compute below
        if (s < NSTAGE - 1) {
            const __bf16* wsrc = wmats + ((s + 1) << 14);
            #pragma unroll
            for (int i = 0; i < 8; ++i)
                wpre[i] = *(const bf16x8*)(wsrc + i * 2048 + tid * 8);
        }
        if (!activeW) continue;

        // acc C-init = bias for this stage (folds the bias add into MFMA)
        {
            const float* bias = (s == 6) ? blin
                              : ((s & 1) ? b2 + (s >> 1) * HDIM
                                         : b1 + (s >> 1) * HDIM);
            #pragma unroll
            for (int mb = 0; mb < 4; ++mb)
                #pragma unroll
                for (int q = 0; q < 4; ++q) {
                    floatx4 bv = *(const floatx4*)(bias + mb * 32 + q * 8 + half * 4);
                    #pragma unroll
                    for (int j = 0; j < 4; ++j) acc[mb][q * 4 + j] = bv[j];
                }
        }

        #pragma unroll
        for (int ks = 0; ks < 8; ++ks) {
            bf16x8 bfrag = frag_from(bw[ks][0], bw[ks][1], bw[ks][2], bw[ks][3]);
            int krow = ks * 2 + half;
            #pragma unroll
            for (int mb = 0; mb < 4; ++mb) {
                int mr = mb * 32 + l31;
                bf16x8 afrag = *(const bf16x8*)(&wlds[(mr << 7) + ((krow ^ (mr & 7)) << 3)]);
                acc[mb] = __builtin_amdgcn_mfma_f32_32x32x16_bf16(afrag, bfrag, acc[mb], 0, 0, 0);
            }
        }

        if (s == 6) {
            // final silu IN-PLACE into acc (bias already included via C-init)
            #pragma unroll
            for (int mb = 0; mb < 4; ++mb)
                #pragma unroll
                for (int r = 0; r < 16; ++r)
                    acc[mb][r] = silu_f(acc[mb][r]);
        } else if ((s & 1) == 0) {
            // h = silu(acc); X unchanged; build next-stage B-fragments
            #pragma unroll
            for (int ks = 0; ks < 8; ++ks) {
                int mb = ks >> 1, qa = (ks & 1) * 2, qb = qa + 1;
                BUILD_BW(ks,
                    silu_f(acc[mb][qa * 4 + 0]), silu_f(acc[mb][qa * 4 + 1]),
                    silu_f(acc[mb][qa * 4 + 2]), silu_f(acc[mb][qa * 4 + 3]),
                    silu_f(acc[mb][qb * 4 + 0]), silu_f(acc[mb][qb * 4 + 1]),
                    silu_f(acc[mb][qb * 4 + 2]), silu_f(acc[mb][qb * 4 + 3]));
            }
        } else {
            // X += acc (residual); act = (s==5) ? X : silu(X)
            #pragma unroll
            for (int ks = 0; ks < 8; ++ks) {
                int mb = ks >> 1, qa = (ks & 1) * 2, qb = qa + 1;
                float va[4], vb[4];
                #pragma unroll
                for (int j = 0; j < 4; ++j) {
                    float nx = X[mb][qa][j] + acc[mb][qa * 4 + j];
                    X[mb][qa][j] = nx;
                    va[j] = (s == 5) ? nx : silu_f(nx);
                }
                #pragma unroll
                for (int j = 0; j < 4; ++j) {
                    float nx = X[mb][qb][j] + acc[mb][qb * 4 + j];
                    X[mb][qb][j] = nx;
                    vb[j] = (s == 5) ? nx : silu_f(nx);
                }
                BUILD_BW(ks, va[0], va[1], va[2], va[3],
                             vb[0], vb[1], vb[2], vb[3]);
            }
        }
    }

    // ---- epilogue: all waves must be done with wlds before overlay ----
    // Two 64-feat passes through a 4*32*72-float buffer (wave-private).
    __syncthreads();
    if (activeW) {
        const int ebase = tile * 32;
        const int cnt = min(32, E - ebase);
        float* yrow = ybuf + (w * 32 + l31) * 72;
        const float* yb = ybuf + w * 32 * 72;
        #pragma unroll
        for (int p = 0; p < 2; ++p) {
            #pragma unroll
            for (int mbh = 0; mbh < 2; ++mbh) {
                int mb = 2 * p + mbh;
                #pragma unroll
                for (int q = 0; q < 4; ++q) {
                    int f0 = mbh * 32 + q * 8 + half * 4;   // within-pass feat
                    floatx4 v;
                    for (int j = 0; j < 4; ++j) v[j] = acc[mb][q * 4 + j];
                    *(floatx4*)(yrow + f0) = v;
                }
            }
            // wave-private segmented accumulate + atomic row-writes
            int cur = __builtin_amdgcn_readlane(mynode, 0);
            float a0 = 0.f;
            for (int e = 0; e < cnt; ++e) {
                int node = __builtin_amdgcn_readlane(mynode, e);
                if (node != cur) {
                    unsafeAtomicAdd(out + (size_t)cur * HDIM + p * 64 + lane, a0);
                    cur = node; a0 = 0.f;
                }
                a0 += yb[e * 72 + lane];
            }
            unsafeAtomicAdd(out + (size_t)cur * HDIM + p * 64 + lane, a0);
        }
    }
    #undef BUILD_BW
}

extern "C" void kernel_launch(void* const* d_in, const int* in_sizes, int n_in,
                              void* d_out, int out_size, void* d_ws, size_t ws_size,
                              hipStream_t stream) {
    const float* m      = (const float*)d_in[0];
    const int* edge_idx = (const int*)d_in[1];
    const float* W1     = (const float*)d_in[3];
    const float* b1     = (const float*)d_in[4];
    const float* W2     = (const float*)d_in[5];
    const float* b2     = (const float*)d_in[6];
    const float* Wlin   = (const float*)d_in[7];
    const float* blin   = (const float*)d_in[8];

    int E = in_sizes[0] / HDIM;
    int N = out_size / HDIM;
    const int* tgt = edge_idx + E;

    int nblk = (E + CHUNK - 1) >> CHUNK_LOG;   // 8192-edge chunks (62 for E=500k)

    // workspace layout (256B-aligned)
    char* ws = (char*)d_ws;
    size_t off = 0;
    auto align_up = [](size_t v) { return (v + 255) & ~(size_t)255; };

    __bf16* wbf = (__bf16*)(ws + off);
    off = align_up(off + (size_t)NSTAGE * HDIM * HDIM * sizeof(__bf16));
    unsigned short* rank = (unsigned short*)(ws + off);
    off = align_up(off + (size_t)E * sizeof(unsigned short));
    int* hb = (int*)(ws + off);
    off = align_up(off + (size_t)nblk * N * sizeof(int));
    int* tot = (int*)(ws + off);
    off = align_up(off + (size_t)N * sizeof(int));
    int* base = (int*)(ws + off);
    off = align_up(off + (size_t)N * sizeof(int));
    int* perm = (int*)(ws + off);
    off = align_up(off + (size_t)E * sizeof(int));
    int* snode = (int*)(ws + off);
    off = align_up(off + (size_t)E * sizeof(int));

    hipMemsetAsync(d_out, 0, (size_t)out_size * sizeof(float), stream);

    convert_weights<<<(NSTAGE * HDIM * HDIM + 255) / 256, 256, 0, stream>>>(W1, W2, Wlin, wbf);

    // atomic-free counting sort
    hist_rank_kernel<<<nblk, 1024, 0, stream>>>(tgt, rank, hb, E, N);
    colsum_kernel<<<(N + 255) / 256, 256, 0, stream>>>(hb, tot, nblk, N);
    scan_kernel<<<1, 1024, 0, stream>>>(tot, base, N);
    offsets_kernel<<<(N + 255) / 256, 256, 0, stream>>>(hb, base, nblk, N);
    emit_perm_kernel<<<(E + 255) / 256, 256, 0, stream>>>(tgt, rank, hb, perm, snode, E, N);

    int ntiles  = (E + 31) / 32;
    int nblocks = (ntiles + 3) / 4;
    fused_mlp_scatter<<<nblocks, 256, 0, stream>>>(m, perm, snode, wbf, b1, b2, blin,
                                                   (float*)d_out, E, ntiles);
}

// Round 4
// 607.032 us; speedup vs baseline: 1.2568x; 1.2568x over previous
//
#include <hip/hip_runtime.h>
#include <hip/hip_bf16.h>

#define HDIM 128
#define NSTAGE 7
#define CHUNK_LOG 13
#define CHUNK (1 << CHUNK_LOG)

typedef __bf16 bf16x8 __attribute__((ext_vector_type(8)));
typedef __bf16 bf16x2 __attribute__((ext_vector_type(2)));
typedef float floatx16 __attribute__((ext_vector_type(16)));
typedef float floatx4 __attribute__((ext_vector_type(4)));
typedef int intx4 __attribute__((ext_vector_type(4)));

__device__ __forceinline__ float silu_f(float x) {
    return x * __builtin_amdgcn_rcpf(1.0f + __expf(-x));
}

__device__ __forceinline__ int pack2(float a, float b) {
    bf16x2 h;
    h[0] = (__bf16)a;
    h[1] = (__bf16)b;
    return __builtin_bit_cast(int, h);
}

__device__ __forceinline__ bf16x8 frag_from(int w0, int w1, int w2, int w3) {
    intx4 v; v[0] = w0; v[1] = w1; v[2] = w2; v[3] = w3;
    return __builtin_bit_cast(bf16x8, v);
}

// async global->LDS, 16B per lane; LDS dest = wave-uniform base + lane*16.
__device__ __forceinline__ void gload_lds16(const void* g, void* l) {
    __builtin_amdgcn_global_load_lds(
        (const __attribute__((address_space(1))) unsigned int*)g,
        (__attribute__((address_space(3))) unsigned int*)l, 16, 0, 0);
}

// Weights -> bf16, stage order W1[0],W2[0],W1[1],W2[1],W1[2],W2[2],Wlin.
// XOR swizzle on 16B chunks: [m][k] -> m*128 + ((k>>3)^(m&7))*8 + (k&7).
__global__ void convert_weights(const float* __restrict__ W1,
                                const float* __restrict__ W2,
                                const float* __restrict__ Wlin,
                                __bf16* __restrict__ dst) {
    int idx = blockIdx.x * blockDim.x + threadIdx.x;
    if (idx >= NSTAGE * HDIM * HDIM) return;
    int s    = idx >> 14;
    int rem  = idx & 16383;
    int mrow = rem >> 7;
    int k    = rem & 127;
    const float* src;
    if (s == 6) src = Wlin;
    else {
        int l = s >> 1;
        src = ((s & 1) ? W2 : W1) + l * HDIM * HDIM;
    }
    float v = src[mrow * HDIM + k];
    int dsti = (s << 14) + (mrow << 7) + ((((k >> 3) ^ (mrow & 7)) << 3) | (k & 7));
    dst[dsti] = (__bf16)v;
}

// ---- atomic-free counting sort of edges by target node ----
__global__ __launch_bounds__(1024) void hist_rank_kernel(
    const int* __restrict__ tgt,
    unsigned short* __restrict__ rank,
    int* __restrict__ hb,
    int E, int N)
{
    __shared__ int lh[10240];   // N = 10000 for this problem
    for (int i = threadIdx.x; i < N; i += 1024) lh[i] = 0;
    __syncthreads();
    int ebase = blockIdx.x << CHUNK_LOG;
    int eend  = min(ebase + CHUNK, E);
    for (int e = ebase + (int)threadIdx.x; e < eend; e += 1024) {
        int node = tgt[e];
        int r = atomicAdd(&lh[node], 1);   // LDS atomic — fast
        rank[e] = (unsigned short)r;       // coalesced
    }
    __syncthreads();
    int* row = hb + (size_t)blockIdx.x * N;
    for (int i = threadIdx.x; i < N; i += 1024) row[i] = lh[i];  // coalesced
}

__global__ void colsum_kernel(const int* __restrict__ hb, int* __restrict__ tot,
                              int nblk, int N) {
    int n = blockIdx.x * blockDim.x + threadIdx.x;
    if (n >= N) return;
    int s = 0;
    for (int b = 0; b < nblk; ++b) s += hb[(size_t)b * N + n];
    tot[n] = s;
}

__global__ __launch_bounds__(1024) void scan_kernel(const int* __restrict__ hist,
                                                    int* __restrict__ cursor, int N) {
    __shared__ int part[1024];
    int t = threadIdx.x;
    int per = (N + 1023) >> 10;
    int lo = t * per, hi = min(lo + per, N);
    int s = 0;
    for (int i = lo; i < hi; ++i) s += hist[i];
    part[t] = s;
    __syncthreads();
    for (int d = 1; d < 1024; d <<= 1) {
        int v = (t >= d) ? part[t - d] : 0;
        __syncthreads();
        part[t] += v;
        __syncthreads();
    }
    int off = (t == 0) ? 0 : part[t - 1];
    for (int i = lo; i < hi; ++i) { cursor[i] = off; off += hist[i]; }
}

__global__ void offsets_kernel(int* __restrict__ hb, const int* __restrict__ base,
                               int nblk, int N) {
    int n = blockIdx.x * blockDim.x + threadIdx.x;
    if (n >= N) return;
    int run = base[n];
    for (int b = 0; b < nblk; ++b) {
        size_t idx = (size_t)b * N + n;
        int c = hb[idx];
        hb[idx] = run;
        run += c;
    }
}

__global__ void emit_perm_kernel(const int* __restrict__ tgt,
                                 const unsigned short* __restrict__ rank,
                                 const int* __restrict__ hb,
                                 int* __restrict__ perm, int* __restrict__ snode,
                                 int E, int N) {
    int e = blockIdx.x * blockDim.x + threadIdx.x;
    if (e >= E) return;
    int node = tgt[e];
    int b = e >> CHUNK_LOG;
    int pos = hb[(size_t)b * N + node] + (int)rank[e];
    perm[pos] = e;
    snode[pos] = node;
}

// One wave owns 32 sorted-order edges end-to-end; residual X in fp32 regs.
// Matmuls transposed: D[feat][edge] via mfma_f32_32x32x16_bf16.
// C/D: edge=lane&31, feat=mb*32+(reg&3)+8*(reg>>2)+4*(lane>>5).
//
// Activations live ENTIRELY IN REGISTERS (verified correct in r3: the
// cross-half exchange via __shfl_xor(.,32) + selects). Bias folded into
// the MFMA C-init.
//
// Weight staging: __builtin_amdgcn_global_load_lds (16B/lane) into a
// DOUBLE-BUFFERED 2x32KB LDS. Swizzle is pre-applied in wmats, so the LDS
// image is a linear copy (legal gload_lds pattern: uniform base+lane*16).
// Stage s+1's loads are issued right after stage s's barrier into the other
// buffer -> one barrier per stage, latency hidden under compute, and the
// wpre register pipeline (32 VGPRs) is GONE -> no spills at (256,2).
__global__ __launch_bounds__(256, 2) void fused_mlp_scatter(
    const float* __restrict__ m,
    const int* __restrict__ perm,
    const int* __restrict__ snode,
    const __bf16* __restrict__ wmats,
    const float* __restrict__ b1,
    const float* __restrict__ b2,
    const float* __restrict__ blin,
    float* __restrict__ out,
    int E, int ntiles)
{
    __shared__ __align__(16) char smem[65536];   // 2x32KB weight dbuf
    float* ybuf = (float*)smem;                  // 4*32*72 f32 epilogue overlay

    const int tid  = threadIdx.x;
    const int w    = tid >> 6;
    const int lane = tid & 63;
    const int l31  = lane & 31;
    const int half = lane >> 5;

    const int tile    = blockIdx.x * 4 + w;
    const bool activeW = (tile < ntiles);
    const int pos = tile * 32 + l31;
    const bool evalid = activeW && (pos < E);

    int eidx = 0, mynode = 0;
    if (evalid) { eidx = perm[pos]; mynode = snode[pos]; }

    floatx4 X[4][4];
    floatx16 acc[4];
    int bw[8][4];   // B-fragments for current stage, fully static-indexed

    #define BUILD_BW(KS, VA0,VA1,VA2,VA3, VB0,VB1,VB2,VB3) do {              \
        int A0_ = pack2((VA0), (VA1)); int A1_ = pack2((VA2), (VA3));        \
        int B0_ = pack2((VB0), (VB1)); int B1_ = pack2((VB2), (VB3));        \
        int N0_ = half ? A0_ : B0_;  int N1_ = half ? A1_ : B1_;             \
        int S0_ = __shfl_xor(N0_, 32, 64);                                   \
        int S1_ = __shfl_xor(N1_, 32, 64);                                   \
        bw[KS][0] = half ? S0_ : A0_;  bw[KS][1] = half ? S1_ : A1_;         \
        bw[KS][2] = half ? B0_ : S0_;  bw[KS][3] = half ? B1_ : S1_;         \
    } while (0)

    // per-wave staging addresses: wave w copies bytes [w*1024 + i*4096 ... +1KB)
    const char* gbase = (const char*)wmats + w * 1024 + lane * 16;
    char* lbase = smem + w * 1024;

    // prologue: issue stage-0 weight loads into buffer 0
    #pragma unroll
    for (int i = 0; i < 8; ++i)
        gload_lds16(gbase + i * 4096, lbase + i * 4096);

    if (activeW) {
        const float* mrow = m + (size_t)eidx * HDIM;
        #pragma unroll
        for (int mb = 0; mb < 4; ++mb)
            #pragma unroll
            for (int q = 0; q < 4; ++q) {
                int f0 = mb * 32 + q * 8 + half * 4;
                X[mb][q] = *(const floatx4*)(mrow + f0);
            }
        // initial activations: silu(X) -> in-register B-fragments
        #pragma unroll
        for (int ks = 0; ks < 8; ++ks) {
            int mb = ks >> 1, qa = (ks & 1) * 2, qb = qa + 1;
            BUILD_BW(ks,
                silu_f(X[mb][qa][0]), silu_f(X[mb][qa][1]),
                silu_f(X[mb][qa][2]), silu_f(X[mb][qa][3]),
                silu_f(X[mb][qb][0]), silu_f(X[mb][qb][1]),
                silu_f(X[mb][qb][2]), silu_f(X[mb][qb][3]));
        }
    }

    #pragma unroll
    for (int s = 0; s < NSTAGE; ++s) {
        // drains vmcnt -> buf[s&1] weights are resident; also all waves are
        // done reading buf[(s&1)^1] (their previous compute phase ended
        // before this barrier), so prefetching into it below is race-free.
        __syncthreads();
        if (s < NSTAGE - 1) {
            const char* gsrc = (const char*)wmats + (((s + 1) << 14) * 2) + w * 1024 + lane * 16;
            char* ldst = smem + (((s + 1) & 1) << 15) + w * 1024;
            #pragma unroll
            for (int i = 0; i < 8; ++i)
                gload_lds16(gsrc + i * 4096, ldst + i * 4096);
        }
        if (!activeW) continue;

        const __bf16* wl = (const __bf16*)(smem + ((s & 1) << 15));

        // acc C-init = bias for this stage (folds the bias add into MFMA)
        {
            const float* bias = (s == 6) ? blin
                              : ((s & 1) ? b2 + (s >> 1) * HDIM
                                         : b1 + (s >> 1) * HDIM);
            #pragma unroll
            for (int mb = 0; mb < 4; ++mb)
                #pragma unroll
                for (int q = 0; q < 4; ++q) {
                    floatx4 bv = *(const floatx4*)(bias + mb * 32 + q * 8 + half * 4);
                    #pragma unroll
                    for (int j = 0; j < 4; ++j) acc[mb][q * 4 + j] = bv[j];
                }
        }

        #pragma unroll
        for (int ks = 0; ks < 8; ++ks) {
            bf16x8 bfrag = frag_from(bw[ks][0], bw[ks][1], bw[ks][2], bw[ks][3]);
            int krow = ks * 2 + half;
            #pragma unroll
            for (int mb = 0; mb < 4; ++mb) {
                int mr = mb * 32 + l31;
                bf16x8 afrag = *(const bf16x8*)(&wl[(mr << 7) + ((krow ^ (mr & 7)) << 3)]);
                acc[mb] = __builtin_amdgcn_mfma_f32_32x32x16_bf16(afrag, bfrag, acc[mb], 0, 0, 0);
            }
        }

        if (s == 6) {
            // final silu IN-PLACE into acc (bias already included via C-init)
            #pragma unroll
            for (int mb = 0; mb < 4; ++mb)
                #pragma unroll
                for (int r = 0; r < 16; ++r)
                    acc[mb][r] = silu_f(acc[mb][r]);
        } else if ((s & 1) == 0) {
            // h = silu(acc); X unchanged; build next-stage B-fragments
            #pragma unroll
            for (int ks = 0; ks < 8; ++ks) {
                int mb = ks >> 1, qa = (ks & 1) * 2, qb = qa + 1;
                BUILD_BW(ks,
                    silu_f(acc[mb][qa * 4 + 0]), silu_f(acc[mb][qa * 4 + 1]),
                    silu_f(acc[mb][qa * 4 + 2]), silu_f(acc[mb][qa * 4 + 3]),
                    silu_f(acc[mb][qb * 4 + 0]), silu_f(acc[mb][qb * 4 + 1]),
                    silu_f(acc[mb][qb * 4 + 2]), silu_f(acc[mb][qb * 4 + 3]));
            }
        } else {
            // X += acc (residual); act = (s==5) ? X : silu(X)
            #pragma unroll
            for (int ks = 0; ks < 8; ++ks) {
                int mb = ks >> 1, qa = (ks & 1) * 2, qb = qa + 1;
                float va[4], vb[4];
                #pragma unroll
                for (int j = 0; j < 4; ++j) {
                    float nx = X[mb][qa][j] + acc[mb][qa * 4 + j];
                    X[mb][qa][j] = nx;
                    va[j] = (s == 5) ? nx : silu_f(nx);
                }
                #pragma unroll
                for (int j = 0; j < 4; ++j) {
                    float nx = X[mb][qb][j] + acc[mb][qb * 4 + j];
                    X[mb][qb][j] = nx;
                    vb[j] = (s == 5) ? nx : silu_f(nx);
                }
                BUILD_BW(ks, va[0], va[1], va[2], va[3],
                             vb[0], vb[1], vb[2], vb[3]);
            }
        }
    }

    // ---- epilogue: all waves done with weight LDS before ybuf overlay ----
    // Two 64-feat passes through a 4*32*72-float buffer (wave-private).
    __syncthreads();
    if (activeW) {
        const int ebase = tile * 32;
        const int cnt = min(32, E - ebase);
        float* yrow = ybuf + (w * 32 + l31) * 72;
        const float* yb = ybuf + w * 32 * 72;
        #pragma unroll
        for (int p = 0; p < 2; ++p) {
            #pragma unroll
            for (int mbh = 0; mbh < 2; ++mbh) {
                int mb = 2 * p + mbh;
                #pragma unroll
                for (int q = 0; q < 4; ++q) {
                    int f0 = mbh * 32 + q * 8 + half * 4;   // within-pass feat
                    floatx4 v;
                    for (int j = 0; j < 4; ++j) v[j] = acc[mb][q * 4 + j];
                    *(floatx4*)(yrow + f0) = v;
                }
            }
            // wave-private segmented accumulate + atomic row-writes
            int cur = __builtin_amdgcn_readlane(mynode, 0);
            float a0 = 0.f;
            for (int e = 0; e < cnt; ++e) {
                int node = __builtin_amdgcn_readlane(mynode, e);
                if (node != cur) {
                    unsafeAtomicAdd(out + (size_t)cur * HDIM + p * 64 + lane, a0);
                    cur = node; a0 = 0.f;
                }
                a0 += yb[e * 72 + lane];
            }
            unsafeAtomicAdd(out + (size_t)cur * HDIM + p * 64 + lane, a0);
        }
    }
    #undef BUILD_BW
}

extern "C" void kernel_launch(void* const* d_in, const int* in_sizes, int n_in,
                              void* d_out, int out_size, void* d_ws, size_t ws_size,
                              hipStream_t stream) {
    const float* m      = (const float*)d_in[0];
    const int* edge_idx = (const int*)d_in[1];
    const float* W1     = (const float*)d_in[3];
    const float* b1     = (const float*)d_in[4];
    const float* W2     = (const float*)d_in[5];
    const float* b2     = (const float*)d_in[6];
    const float* Wlin   = (const float*)d_in[7];
    const float* blin   = (const float*)d_in[8];

    int E = in_sizes[0] / HDIM;
    int N = out_size / HDIM;
    const int* tgt = edge_idx + E;

    int nblk = (E + CHUNK - 1) >> CHUNK_LOG;   // 8192-edge chunks (62 for E=500k)

    // workspace layout (256B-aligned)
    char* ws = (char*)d_ws;
    size_t off = 0;
    auto align_up = [](size_t v) { return (v + 255) & ~(size_t)255; };

    __bf16* wbf = (__bf16*)(ws + off);
    off = align_up(off + (size_t)NSTAGE * HDIM * HDIM * sizeof(__bf16));
    unsigned short* rank = (unsigned short*)(ws + off);
    off = align_up(off + (size_t)E * sizeof(unsigned short));
    int* hb = (int*)(ws + off);
    off = align_up(off + (size_t)nblk * N * sizeof(int));
    int* tot = (int*)(ws + off);
    off = align_up(off + (size_t)N * sizeof(int));
    int* base = (int*)(ws + off);
    off = align_up(off + (size_t)N * sizeof(int));
    int* perm = (int*)(ws + off);
    off = align_up(off + (size_t)E * sizeof(int));
    int* snode = (int*)(ws + off);
    off = align_up(off + (size_t)E * sizeof(int));

    hipMemsetAsync(d_out, 0, (size_t)out_size * sizeof(float), stream);

    convert_weights<<<(NSTAGE * HDIM * HDIM + 255) / 256, 256, 0, stream>>>(W1, W2, Wlin, wbf);

    // atomic-free counting sort
    hist_rank_kernel<<<nblk, 1024, 0, stream>>>(tgt, rank, hb, E, N);
    colsum_kernel<<<(N + 255) / 256, 256, 0, stream>>>(hb, tot, nblk, N);
    scan_kernel<<<1, 1024, 0, stream>>>(tot, base, N);
    offsets_kernel<<<(N + 255) / 256, 256, 0, stream>>>(hb, base, nblk, N);
    emit_perm_kernel<<<(E + 255) / 256, 256, 0, stream>>>(tgt, rank, hb, perm, snode, E, N);

    int ntiles  = (E + 31) / 32;
    int nblocks = (ntiles + 3) / 4;
    fused_mlp_scatter<<<nblocks, 256, 0, stream>>>(m, perm, snode, wbf, b1, b2, blin,
                                                   (float*)d_out, E, ntiles);
}